// Round 1
// 418.288 us; speedup vs baseline: 1.3344x; 1.3344x over previous
//
#include <hip/hip_runtime.h>

// MultiHeadLinearAttention (B=8,S=4096,IN=1024,H=16,D=64). ALL I/O fp32.
//   k = x@wk + bk ; K = elu(k)+1 ; v = x@wv + bv
//   KV[b,c] = sum_s K*v (elementwise), Ksum[b,c] = sum_s K
//   attn = Q*KV/(Q*Ksum+1e-6) ≈ KV/Ksum  (s-independent broadcast)
//   out[b,s,:] = gelu_tanh((KV_b/Ksum_b)@wo + bo)
// v3: kv_gemm_fast rebuilt as deep-pipelined dual-B GEMM:
//   BM=256, BN=128 (x2 matrices), BK=64, 512 thr / 8 waves (4m x 2n).
//   T2 XOR-swizzled LDS (inverse-swizzled gload_lds source, swizzled reads),
//   T3/T4 double-buffer + counted s_waitcnt vmcnt(8) (no in-loop drain),
//   T5 setprio around 16-MFMA phase clusters, T1 bijective XCD swizzle.

#define SEQ   4096
#define MROWS 32768
#define KDIM  1024
#define HD    1024

typedef __bf16 bf16x8 __attribute__((ext_vector_type(8)));
typedef float floatx4 __attribute__((ext_vector_type(4)));

__device__ __forceinline__ unsigned short f2bf(float f) {
    unsigned int u = __float_as_uint(f);
    u += 0x7fffu + ((u >> 16) & 1u);   // RNE
    return (unsigned short)(u >> 16);
}
__device__ __forceinline__ void cvt8(const float* __restrict__ p, unsigned short* d) {
    const float4 a = *(const float4*)p;
    const float4 b = *(const float4*)(p + 4);
    d[0] = f2bf(a.x); d[1] = f2bf(a.y); d[2] = f2bf(a.z); d[3] = f2bf(a.w);
    d[4] = f2bf(b.x); d[5] = f2bf(b.y); d[6] = f2bf(b.z); d[7] = f2bf(b.w);
}

typedef const __attribute__((address_space(1))) unsigned int* gas_t;
typedef __attribute__((address_space(3))) unsigned int* las_t;
__device__ __forceinline__ void async16(const void* g, void* l) {
    // one global_load_lds_dwordx4: LDS dst = readfirstlane(l) + lane*16
    __builtin_amdgcn_global_load_lds((gas_t)g, (las_t)l, 16, 0, 0);
}

// ---------- Prepass A: x fp32 -> bf16 ----------
__global__ __launch_bounds__(256)
void cvt_x(const float* __restrict__ x, unsigned short* __restrict__ xb)
{
    const size_t p = ((size_t)blockIdx.x * 256 + threadIdx.x) * 8;
    union { uint4 u; unsigned short s[8]; } o;
    cvt8(x + p, o.s);
    *(uint4*)(xb + p) = o.u;
}

// ---------- Prepass B: W[k][n] fp32 -> WT[n][k] bf16 (64x64 tiles) ----------
__global__ __launch_bounds__(256)
void transpose_w(const float* __restrict__ wk, const float* __restrict__ wv,
                 unsigned short* __restrict__ wkT, unsigned short* __restrict__ wvT)
{
    __shared__ alignas(16) unsigned short Ts[64][72];
    const float* W = blockIdx.z ? wv : wk;
    unsigned short* WT = blockIdx.z ? wvT : wkT;
    const int k0 = blockIdx.x * 64, n0 = blockIdx.y * 64;
    const int t = threadIdx.x;
    const int r4 = (t >> 4) * 4, c4 = (t & 15) * 4;
#pragma unroll
    for (int i = 0; i < 4; i++) {
        const float4 f = *(const float4*)(W + (size_t)(k0 + r4 + i) * HD + n0 + c4);
        Ts[c4 + 0][r4 + i] = f2bf(f.x);
        Ts[c4 + 1][r4 + i] = f2bf(f.y);
        Ts[c4 + 2][r4 + i] = f2bf(f.z);
        Ts[c4 + 3][r4 + i] = f2bf(f.w);
    }
    __syncthreads();
    const int rr = t >> 3, cc = (t & 7) * 8;
#pragma unroll
    for (int h = 0; h < 2; h++)
        *(uint4*)(WT + (size_t)(n0 + rr + h * 32) * KDIM + k0 + cc) =
            *(const uint4*)&Ts[rr + h * 32][cc];
}

// ---------- Kernel 1 (fast): deep-pipelined dual-B GEMM + fused reduction ----
// grid 1024 blocks x 512 thr. BM=256 rows, BN=128 cols for BOTH K and V.
// LDS 128 KiB: A[2][256][64], Bk[2][128][64], Bv[2][128][64] bf16,
// XOR-swizzled (16B unit ^= row&7). 16 K-tiles of 64; per tile: 4 phases of
// 16 MFMA/wave; tile t+2 staged after freeing its buffer; vmcnt(8) boundary.
__global__ __launch_bounds__(512, 2)
void kv_gemm_fast(const unsigned short* __restrict__ xb,
                  const unsigned short* __restrict__ wkT,
                  const unsigned short* __restrict__ wvT,
                  const float* __restrict__ bk, const float* __restrict__ bv,
                  float2* __restrict__ KVZ)
{
    __shared__ alignas(16) unsigned short As[2][256 * 64];   // 64 KiB
    __shared__ alignas(16) unsigned short Bks[2][128 * 64];  // 32 KiB
    __shared__ alignas(16) unsigned short Bvs[2][128 * 64];  // 32 KiB

    const int t = threadIdx.x;

    // T1: bijective XCD decode. 1024 blocks = 8 XCDs x 128. ntile innermost
    // so the 8 blocks sharing one A-panel are consecutive on ONE XCD's L2.
    const int id = blockIdx.x;
    const int xcd = id & 7, o = id >> 3;
    const int mtile = xcd * 16 + (o >> 3);   // 0..127
    const int ntile = o & 7;                 // 0..7
    const int m0 = mtile * 256;
    const int n0 = ntile * 128;
    const int b  = m0 >> 12;

    const int w = t >> 6, lane = t & 63;
    const int wm = w >> 1, wn = w & 1;           // 4m x 2n wave grid
    const int lrow = lane & 15, quad = lane >> 4;
    const int swz = lane & 7;                    // == (frag row) & 7

    // Staging geometry: lane t covers row (chunk*64 + t/8), 16B unit (t&7).
    // Inverse-swizzle the GLOBAL source so linear gload_lds dst + swizzled
    // read compose to identity (rule #21).
    const int srow  = t >> 3;                    // 0..63
    const int sunit = (t & 7) ^ (srow & 7);
    const unsigned short* gA = xb  + (size_t)(m0 + srow) * KDIM + sunit * 8;
    const unsigned short* gK = wkT + (size_t)(n0 + srow) * KDIM + sunit * 8;
    const unsigned short* gV = wvT + (size_t)(n0 + srow) * KDIM + sunit * 8;

#define STAGE(c, tk) do {                                                     \
        const int koff_ = (tk) * 64;                                          \
        async16(gA + koff_,                    &As[c][         t * 8]);       \
        async16(gA + koff_ +  64 * KDIM,       &As[c][ 4096 +  t * 8]);       \
        async16(gA + koff_ + 128 * KDIM,       &As[c][ 8192 +  t * 8]);       \
        async16(gA + koff_ + 192 * KDIM,       &As[c][12288 +  t * 8]);       \
        async16(gK + koff_,                    &Bks[c][        t * 8]);       \
        async16(gK + koff_ +  64 * KDIM,       &Bks[c][4096 +  t * 8]);       \
        async16(gV + koff_,                    &Bvs[c][        t * 8]);       \
        async16(gV + koff_ +  64 * KDIM,       &Bvs[c][4096 +  t * 8]);       \
    } while (0)

    STAGE(0, 0);
    STAGE(1, 1);

    floatx4 accK[4][4], accV[4][4];
#pragma unroll
    for (int i = 0; i < 4; i++)
#pragma unroll
        for (int j = 0; j < 4; j++) {
            accK[i][j] = (floatx4){0.f, 0.f, 0.f, 0.f};
            accV[i][j] = (floatx4){0.f, 0.f, 0.f, 0.f};
        }

    // tile0 ready when only tile1's 8 loads remain outstanding
    asm volatile("s_waitcnt vmcnt(8)" ::: "memory");
    __builtin_amdgcn_s_barrier();

    for (int tk = 0; tk < 16; ++tk) {
        const int c = tk & 1;
        const unsigned short* A  = As[c];
        const unsigned short* BK = Bks[c];
        const unsigned short* BV = Bvs[c];

#pragma unroll
        for (int kk = 0; kk < 2; ++kk) {
            bf16x8 af[4];
#pragma unroll
            for (int mi = 0; mi < 4; ++mi) {
                const int row = wm * 64 + mi * 16 + lrow;
                af[mi] = *(const bf16x8*)&A[row * 64 + (((kk * 4 + quad) ^ swz) << 3)];
            }
#pragma unroll
            for (int mat = 0; mat < 2; ++mat) {
                const unsigned short* Bp = mat ? BV : BK;
                bf16x8 bf[4];
#pragma unroll
                for (int ni = 0; ni < 4; ++ni) {
                    const int row = wn * 64 + ni * 16 + lrow;
                    bf[ni] = *(const bf16x8*)&Bp[row * 64 + (((kk * 4 + quad) ^ swz) << 3)];
                }
                __builtin_amdgcn_s_barrier();      // cluster waves per phase
                __builtin_amdgcn_s_setprio(1);
                if (mat == 0) {
#pragma unroll
                    for (int mi = 0; mi < 4; ++mi)
#pragma unroll
                        for (int ni = 0; ni < 4; ++ni)
                            accK[mi][ni] = __builtin_amdgcn_mfma_f32_16x16x32_bf16(
                                af[mi], bf[ni], accK[mi][ni], 0, 0, 0);
                } else {
#pragma unroll
                    for (int mi = 0; mi < 4; ++mi)
#pragma unroll
                        for (int ni = 0; ni < 4; ++ni)
                            accV[mi][ni] = __builtin_amdgcn_mfma_f32_16x16x32_bf16(
                                af[mi], bf[ni], accV[mi][ni], 0, 0, 0);
                }
                __builtin_amdgcn_s_setprio(0);
            }
        }

        // tile boundary: all waves done reading buf c -> refill it with t+2,
        // then wait (counted) for tile t+1 and cross the barrier.
        __builtin_amdgcn_s_barrier();
        if (tk + 2 < 16) {
            STAGE(c, tk + 2);
            asm volatile("s_waitcnt vmcnt(8)" ::: "memory");
        } else {
            asm volatile("s_waitcnt vmcnt(0)" ::: "memory");
        }
        __builtin_amdgcn_s_barrier();
    }
#undef STAGE

    // Epilogue: K = elu(k+bk)+1, v += bv; C/D map: col(n)=lrow, row(m)=quad*4+r
#pragma unroll
    for (int ni = 0; ni < 4; ++ni) {
        const int colw = n0 + wn * 64 + ni * 16 + lrow;
        const float bkf = bk[colw];
        const float bvf = bv[colw];
        float pKV = 0.f, pK = 0.f;
#pragma unroll
        for (int mi = 0; mi < 4; ++mi) {
#pragma unroll
            for (int r = 0; r < 4; ++r) {
                const float kv = accK[mi][ni][r] + bkf;
                const float K  = (kv > 0.f) ? (kv + 1.f) : __expf(kv);
                const float vv = accV[mi][ni][r] + bvf;
                pKV += K * vv;
                pK  += K;
            }
        }
        pKV += __shfl_xor(pKV, 16, 64);
        pKV += __shfl_xor(pKV, 32, 64);
        pK  += __shfl_xor(pK, 16, 64);
        pK  += __shfl_xor(pK, 32, 64);
        if (quad == 0) {
            atomicAdd(&KVZ[b * HD + colw].x, pKV);
            atomicAdd(&KVZ[b * HD + colw].y, pK);
        }
    }
}

// ---------- Kernel 1 (fallback, round-4 verified): fp32 staging ----------
__global__ __launch_bounds__(256)
void kv_gemm(const float* __restrict__ x,
             const float* __restrict__ wk, const float* __restrict__ bk,
             const float* __restrict__ wv, const float* __restrict__ bv,
             float2* __restrict__ KVZ)
{
    __shared__ alignas(16) unsigned short As [128][40];
    __shared__ alignas(16) unsigned short BsK[128][40];
    __shared__ alignas(16) unsigned short BsV[128][40];

    const int t = threadIdx.x;
    const int n0 = blockIdx.x * 128;
    const int m0 = blockIdx.y * 128;
    const int b  = m0 >> 12;

    const int wave = t >> 6, lane = t & 63;
    const int wm = wave >> 1, wn = wave & 1;
    const int lrow = lane & 15, quad = lane >> 4;

    floatx4 accK[4][4], accV[4][4];
#pragma unroll
    for (int i = 0; i < 4; i++)
#pragma unroll
        for (int j = 0; j < 4; j++) {
            accK[i][j] = (floatx4){0.f, 0.f, 0.f, 0.f};
            accV[i][j] = (floatx4){0.f, 0.f, 0.f, 0.f};
        }

    const int arow0 = t >> 2, akc = (t & 3) * 8;
    const int bk0 = t >> 4, bnc = (t & 15) * 8;

    for (int k0 = 0; k0 < KDIM; k0 += 32) {
        __syncthreads();
        {
            union { uint4 u; unsigned short s[8]; } ua, ub;
            cvt8(x + (size_t)(m0 + arow0) * KDIM + k0 + akc, ua.s);
            cvt8(x + (size_t)(m0 + arow0 + 64) * KDIM + k0 + akc, ub.s);
            *(uint4*)&As[arow0][akc] = ua.u;
            *(uint4*)&As[arow0 + 64][akc] = ub.u;
        }
        {
            unsigned short k0s[8], k1s[8], v0s[8], v1s[8];
            cvt8(wk + (size_t)(k0 + bk0) * HD + n0 + bnc, k0s);
            cvt8(wk + (size_t)(k0 + bk0 + 16) * HD + n0 + bnc, k1s);
            cvt8(wv + (size_t)(k0 + bk0) * HD + n0 + bnc, v0s);
            cvt8(wv + (size_t)(k0 + bk0 + 16) * HD + n0 + bnc, v1s);
#pragma unroll
            for (int j = 0; j < 8; j++) {
                BsK[bnc + j][bk0]      = k0s[j];
                BsK[bnc + j][bk0 + 16] = k1s[j];
                BsV[bnc + j][bk0]      = v0s[j];
                BsV[bnc + j][bk0 + 16] = v1s[j];
            }
        }
        __syncthreads();

        bf16x8 af[4], bfK[4], bfV[4];
#pragma unroll
        for (int mi = 0; mi < 4; mi++)
            af[mi] = *(const bf16x8*)&As[wm * 64 + mi * 16 + lrow][quad * 8];
#pragma unroll
        for (int ni = 0; ni < 4; ni++) {
            bfK[ni] = *(const bf16x8*)&BsK[wn * 64 + ni * 16 + lrow][quad * 8];
            bfV[ni] = *(const bf16x8*)&BsV[wn * 64 + ni * 16 + lrow][quad * 8];
        }
#pragma unroll
        for (int mi = 0; mi < 4; mi++)
#pragma unroll
            for (int ni = 0; ni < 4; ni++) {
                accK[mi][ni] = __builtin_amdgcn_mfma_f32_16x16x32_bf16(
                    af[mi], bfK[ni], accK[mi][ni], 0, 0, 0);
                accV[mi][ni] = __builtin_amdgcn_mfma_f32_16x16x32_bf16(
                    af[mi], bfV[ni], accV[mi][ni], 0, 0, 0);
            }
    }

#pragma unroll
    for (int ni = 0; ni < 4; ni++) {
        const int colw = n0 + wn * 64 + ni * 16 + lrow;
        const float bkf = bk[colw];
        const float bvf = bv[colw];
        float pKV = 0.f, pK = 0.f;
#pragma unroll
        for (int mi = 0; mi < 4; mi++) {
#pragma unroll
            for (int r = 0; r < 4; r++) {
                const float kk = accK[mi][ni][r] + bkf;
                const float K  = (kk > 0.f) ? (kk + 1.f) : __expf(kk);
                const float vv = accV[mi][ni][r] + bvf;
                pKV += K * vv;
                pK  += K;
            }
        }
        pKV += __shfl_xor(pKV, 16, 64);
        pKV += __shfl_xor(pKV, 32, 64);
        pK  += __shfl_xor(pK, 16, 64);
        pK  += __shfl_xor(pK, 32, 64);
        if (quad == 0) {
            atomicAdd(&KVZ[b * HD + colw].x, pKV);
            atomicAdd(&KVZ[b * HD + colw].y, pK);
        }
    }
}

// ---------- Kernel 2: rowf[b][o] = gelu((KV/Ksum)@wo + bo), fp32 ----------
__global__ __launch_bounds__(256)
void rowgemm(const float2* __restrict__ KVZ,
             const float* __restrict__ wo, const float* __restrict__ bo,
             float* __restrict__ rowf)
{
    __shared__ float a[1024];
    __shared__ float red[4][64];
    const int t = threadIdx.x;
    const int b = blockIdx.x;
    const int o0 = blockIdx.y * 64;

    for (int c = t; c < 1024; c += 256) {
        const float2 z = KVZ[b * HD + c];
        a[c] = z.x / z.y;
    }
    __syncthreads();

    const int cs = t >> 6, oi = t & 63;
    float p = 0.f;
    const int cbeg = cs * 256;
    for (int c = cbeg; c < cbeg + 256; ++c)
        p += a[c] * wo[(size_t)c * HD + o0 + oi];
    red[cs][oi] = p;
    __syncthreads();

    if (t < 64) {
        float v = red[0][t] + red[1][t] + red[2][t] + red[3][t] + bo[o0 + t];
        const float g = 0.5f * v *
            (1.f + tanhf(0.7978845608028654f * (v + 0.044715f * v * v * v)));
        rowf[b * HD + o0 + t] = g;
    }
}

// ---------- Kernel 3: broadcast rowf over S ----------
__global__ __launch_bounds__(256)
void broadcast_rows(const float* __restrict__ rowf, float* __restrict__ out)
{
    const size_t idx = (size_t)blockIdx.x * 256 + threadIdx.x;
    const size_t p = idx * 4;
    const int row = (int)(p >> 10);
    const int b = row >> 12;
    const int col = (int)(p & 1023);
    *(float4*)(out + p) = *(const float4*)(rowf + b * HD + col);
}

extern "C" void kernel_launch(void* const* d_in, const int* in_sizes, int n_in,
                              void* d_out, int out_size, void* d_ws, size_t ws_size,
                              hipStream_t stream)
{
    const float* x  = (const float*)d_in[0];
    const float* wk = (const float*)d_in[3];
    const float* bk = (const float*)d_in[4];
    const float* wv = (const float*)d_in[5];
    const float* bv = (const float*)d_in[6];
    const float* wo = (const float*)d_in[7];
    const float* bo = (const float*)d_in[8];
    float* out = (float*)d_out;

    const size_t NEED = (size_t)72 * 1024 * 1024;
    if (ws_size >= NEED) {
        unsigned short* xb  = (unsigned short*)d_ws;                       // 64 MiB
        unsigned short* wkT = (unsigned short*)((char*)d_ws + (67u << 20));// 2 MiB
        unsigned short* wvT = (unsigned short*)((char*)d_ws + (69u << 20));// 2 MiB
        float2* KVZ = (float2*)((char*)d_ws + (71u << 20));                // 64 KiB
        float* rowf = (float*)((char*)d_ws + (71u << 20) + 65536);         // 32 KiB

        hipMemsetAsync(KVZ, 0, 8 * HD * sizeof(float2), stream);
        cvt_x<<<dim3(MROWS * KDIM / 8 / 256), 256, 0, stream>>>(x, xb);
        transpose_w<<<dim3(16, 16, 2), 256, 0, stream>>>(wk, wv, wkT, wvT);
        kv_gemm_fast<<<dim3(1024), 512, 0, stream>>>(xb, wkT, wvT, bk, bv, KVZ);
        rowgemm<<<dim3(8, 16), 256, 0, stream>>>(KVZ, wo, bo, rowf);
        broadcast_rows<<<dim3((MROWS * HD / 4) / 256), 256, 0, stream>>>(rowf, out);
    } else {
        float2* KVZ = (float2*)d_ws;
        float* rowf = (float*)((char*)d_ws + 65536);
        hipMemsetAsync(KVZ, 0, 8 * HD * sizeof(float2), stream);
        kv_gemm<<<dim3(8, 256), 256, 0, stream>>>(x, wk, bk, wv, bv, KVZ);
        rowgemm<<<dim3(8, 16), 256, 0, stream>>>(KVZ, wo, bo, rowf);
        broadcast_rows<<<dim3((MROWS * HD / 4) / 256), 256, 0, stream>>>(rowf, out);
    }
}